// Round 2
// baseline (121.381 us; speedup 1.0000x reference)
//
#include <hip/hip_runtime.h>
#include <math.h>

// AFM forward: out[b] = linear(b) + softmax-weighted pair-interaction projection.
// B=4096, F=26, d=64, P=325 pairs, af=64.
//
// R9: two m-tiles per iteration + merged 2-way online-softmax update.
// R8 post-mortem: the 256-MiB harness poison fill is unconditional (~44 us,
// 76-78% HBM peak, top-5 every round); afm itself is <43 us and latency-
// bound (R6: no pipe >40% busy). Remaining levers are serial-chain length
// and barrier stragglers:
//  (a) main loop now processes 2 tiles/iter (16 MFMAs of independent work)
//      with ONE softmax chain step: mn=max(m,lga,lgb) (v_max3), one alpha,
//      two e's. Chain 21 steps -> 11; exp 42 -> 33.
//  (b) embedding staging is block-cooperative (all 4 rows spread over 256
//      threads) so the prologue __syncthreads waits on an even load, not
//      the slowest wave's private 208-task loop.
// 1 row/wave, 4 waves/block, single prologue barrier.

#define NF 26
#define NP 325
#define NIT 11           // 11 iterations x 2 tiles x 16 pairs = 352 slots (pads -> -inf)
#define NTILE (NIT * 2)
#define ED 64
#define AF 64
#define NDENSE 13
#define WPB 4            // waves (rows) per block
#define BLOCK (WPB * 64)
#define ESTRIDE 72       // f16 elems per emb row: 144 B (16B-aligned rows)
#define WSTRIDE 72       // f16 elems per w1t row: 144 B (16B-aligned rows)

typedef __attribute__((ext_vector_type(8))) _Float16 half8;
typedef __attribute__((ext_vector_type(4))) float f32x4;

__device__ __forceinline__ half8 bcast8(float v) {
    _Float16 h = (_Float16)v;
    half8 r = { h, h, h, h, h, h, h, h };
    return r;
}

__global__ __launch_bounds__(BLOCK, 4)   // VGPR cap 128 (R4 lesson: never cap below live set)
void afm_kernel(const int*   __restrict__ sparse,   // [B,26]
                const float* __restrict__ dense,    // [B,13]
                const float* __restrict__ etab,     // [V,64]
                const float* __restrict__ ltab,     // [V]
                const float* __restrict__ wdense,   // [13]
                const float* __restrict__ bias,     // [1]
                const float* __restrict__ W1,       // [64][64] f32, d-major
                const float* __restrict__ b1,       // [64]
                const float* __restrict__ w2,       // [64]
                const float* __restrict__ proj,     // [64]
                float*       __restrict__ out,      // [B]
                int B)
{
    const int t    = threadIdx.x;
    const int wave = t >> 6;
    const int lane = t & 63;
    const int qd   = lane >> 4;     // quad 0..3
    const int ln   = lane & 15;

    __shared__ alignas(16) _Float16       w1t_s[AF][WSTRIDE];        //  9216 B (row a, col d)
    __shared__              unsigned short tab_s[NTILE * 16];        //   704 B
    __shared__ alignas(16) _Float16       emb_all[WPB][NF][ESTRIDE]; // 14976 B

    // ---- block-cooperative embedding staging: all WPB rows spread evenly
    //      over 256 threads (832 tasks, 3-4 each), f32 gather -> f16 b128 LDS ----
    for (int task = t; task < WPB * NF * 8; task += BLOCK) {
        int w   = task / (NF * 8);
        int rem = task - w * (NF * 8);
        int f = rem >> 3, c = rem & 7;                   // 8-half chunk
        int rw = blockIdx.x * WPB + w;
        if (rw < B) {
            const float* src = etab + (size_t)sparse[rw * NF + f] * ED + c * 8;
            float4 v0 = *(const float4*)(src);
            float4 v1 = *(const float4*)(src + 4);
            half8 h = { (_Float16)v0.x, (_Float16)v0.y, (_Float16)v0.z, (_Float16)v0.w,
                        (_Float16)v1.x, (_Float16)v1.y, (_Float16)v1.z, (_Float16)v1.w };
            *(half8*)(&emb_all[w][f][c * 8]) = h;
        }
    }

    // ---- block-cooperative W1 -> W1^T staging (L2-hot 16 KB) ----
    for (int idx = t; idx < ED * AF; idx += BLOCK) {
        int d = idx >> 6, a = idx & 63;       // W1 is [d][a]
        w1t_s[a][d] = (_Float16)W1[idx];
    }
    // ---- pair-index table: tab_s[p] = i | j<<8 (slots >= NP stay 0) ----
    for (int p = t; p < NTILE * 16; p += BLOCK) {
        unsigned short v = 0;
        if (p < NP) {
            int rem = p, i = 0;
            while (rem >= NF - 1 - i) { rem -= NF - 1 - i; ++i; }
            v = (unsigned short)(i | ((i + 1 + rem) << 8));
        }
        tab_s[p] = v;
    }

    const int r = blockIdx.x * WPB + wave;   // this wave's batch row
    const bool active = (r < B);

    _Float16 (* __restrict__ emb)[ESTRIDE] = emb_all[wave];
    float lin = 0.f;
    float4 b1v4[4], w2v4[4];

    if (active) {
        // b1/w2 for af = nt*16 + qd*4 + rr  (C-row mapping)
        #pragma unroll
        for (int nt = 0; nt < 4; ++nt) {
            b1v4[nt] = *(const float4*)(b1 + nt * 16 + qd * 4);
            w2v4[nt] = *(const float4*)(w2 + nt * 16 + qd * 4);
        }
        // ---- linear part (wave-local registers) ----
        if (lane < NF) {
            lin = ltab[sparse[r * NF + lane]];
        } else if (lane >= 32 && lane < 32 + NDENSE) {
            int k = lane - 32;
            lin = dense[r * NDENSE + k] * wdense[k];
        }
        #pragma unroll
        for (int off = 32; off >= 1; off >>= 1) lin += __shfl_xor(lin, off, 64);
        lin += bias[0];
    }

    __syncthreads();          // w1t_s/tab_s/emb_all visible
    if (!active) return;      // safe: no barriers after this point

    // ---- W1^T A-operand fragments from LDS:
    //      bfr[nt][kh] = w1t[af = nt*16+ln][k = kh*32 + qd*8 + j] ----
    half8 bfr[4][2];
    #pragma unroll
    for (int nt = 0; nt < 4; ++nt)
        #pragma unroll
        for (int kh = 0; kh < 2; ++kh)
            bfr[nt][kh] = *(const half8*)(&w1t_s[nt * 16 + ln][kh * 32 + qd * 8]);

    // ---- fused main loop: 2 m-tiles/iter, merged 2-way online softmax.
    //      Lane state: m, l, acc0/acc1 (f16, dims qd*8..+7 / 32+qd*8..+7). ----
    float m = -INFINITY, l = 0.f;
    half8 acc0 = bcast8(0.f), acc1 = bcast8(0.f);

    for (int it = 0; it < NIT; ++it) {
        const int pa = it * 32 + ln;          // tile 2*it
        const int pb = pa + 16;               // tile 2*it+1
        unsigned ppa = tab_s[pa];
        unsigned ppb = tab_s[pb];

        int fia = ppa & 0xff, fja = ppa >> 8;
        half8 xa0 = *(const half8*)(&emb[fia][qd * 8])      * *(const half8*)(&emb[fja][qd * 8]);
        half8 xa1 = *(const half8*)(&emb[fia][32 + qd * 8]) * *(const half8*)(&emb[fja][32 + qd * 8]);
        int fib = ppb & 0xff, fjb = ppb >> 8;
        half8 xb0 = *(const half8*)(&emb[fib][qd * 8])      * *(const half8*)(&emb[fjb][qd * 8]);
        half8 xb1 = *(const half8*)(&emb[fib][32 + qd * 8]) * *(const half8*)(&emb[fjb][32 + qd * 8]);

        // logits for both tiles: D[m=af][n=pair=ln]; C rows = qd*4+reg.
        float lgpa[4], lgpb[4];
        #pragma unroll
        for (int nt = 0; nt < 4; ++nt) {
            f32x4 ca = { b1v4[nt].x, b1v4[nt].y, b1v4[nt].z, b1v4[nt].w };
            ca = __builtin_amdgcn_mfma_f32_16x16x32_f16(bfr[nt][0], xa0, ca, 0, 0, 0);
            ca = __builtin_amdgcn_mfma_f32_16x16x32_f16(bfr[nt][1], xa1, ca, 0, 0, 0);
            f32x4 cb = { b1v4[nt].x, b1v4[nt].y, b1v4[nt].z, b1v4[nt].w };
            cb = __builtin_amdgcn_mfma_f32_16x16x32_f16(bfr[nt][0], xb0, cb, 0, 0, 0);
            cb = __builtin_amdgcn_mfma_f32_16x16x32_f16(bfr[nt][1], xb1, cb, 0, 0, 0);
            float ua = fmaf(fmaxf(ca[1], 0.f), w2v4[nt].y, fmaxf(ca[0], 0.f) * w2v4[nt].x);
            float va = fmaf(fmaxf(ca[3], 0.f), w2v4[nt].w, fmaxf(ca[2], 0.f) * w2v4[nt].z);
            lgpa[nt] = ua + va;
            float ub = fmaf(fmaxf(cb[1], 0.f), w2v4[nt].y, fmaxf(cb[0], 0.f) * w2v4[nt].x);
            float vb = fmaf(fmaxf(cb[3], 0.f), w2v4[nt].w, fmaxf(cb[2], 0.f) * w2v4[nt].z);
            lgpb[nt] = ub + vb;
        }
        float lga = (lgpa[0] + lgpa[1]) + (lgpa[2] + lgpa[3]);
        float lgb = (lgpb[0] + lgpb[1]) + (lgpb[2] + lgpb[3]);
        // sum over the 4 qd groups -> full 64-af logits, replicated across qd
        lga += __shfl_xor(lga, 16, 64);
        lga += __shfl_xor(lga, 32, 64);
        lgb += __shfl_xor(lgb, 16, 64);
        lgb += __shfl_xor(lgb, 32, 64);

        if (pa >= NP) lga = -INFINITY;        // pad pairs contribute 0
        if (pb >= NP) lgb = -INFINITY;

        // merged 2-way online-softmax update (one chain step per iteration)
        float mn    = fmaxf(fmaxf(m, lga), lgb);   // v_max3
        float alpha = __expf(m - mn);              // m=-inf first iter -> 0 (mn finite)
        float ea    = __expf(lga - mn);
        float eb    = __expf(lgb - mn);
        l = l * alpha + ea + eb;
        m = mn;
        half8 a8  = bcast8(alpha);
        half8 ea8 = bcast8(ea);
        half8 eb8 = bcast8(eb);
        acc0 = (acc0 * a8 + xa0 * ea8) + xb0 * eb8;   // v_pk_fma_f16
        acc1 = (acc1 * a8 + xa1 * ea8) + xb1 * eb8;
    }

    // ---- merge: lanes sharing qd (ln = bits 0..3) cover all 352 slots ----
    float mg = m;
    #pragma unroll
    for (int off = 1; off <= 8; off <<= 1) mg = fmaxf(mg, __shfl_xor(mg, off, 64));
    const float fac = __expf(m - mg);            // per-lane rescale to global max
    float lsum = l * fac;
    #pragma unroll
    for (int off = 1; off <= 8; off <<= 1) lsum += __shfl_xor(lsum, off, 64);
    // lsum now = global softmax denominator, identical across qd groups

    // proj-dot in-lane (dims qd*8..+7 and 32+qd*8..+7), scaled by fac
    float4 pa4 = *(const float4*)(proj + qd * 8);
    float4 pb4 = *(const float4*)(proj + qd * 8 + 4);
    float4 pc4 = *(const float4*)(proj + 32 + qd * 8);
    float4 pd4 = *(const float4*)(proj + 32 + qd * 8 + 4);
    float rr = (float)acc0[0] * pa4.x + (float)acc0[1] * pa4.y
             + (float)acc0[2] * pa4.z + (float)acc0[3] * pa4.w
             + (float)acc0[4] * pb4.x + (float)acc0[5] * pb4.y
             + (float)acc0[6] * pb4.z + (float)acc0[7] * pb4.w
             + (float)acc1[0] * pc4.x + (float)acc1[1] * pc4.y
             + (float)acc1[2] * pc4.z + (float)acc1[3] * pc4.w
             + (float)acc1[4] * pd4.x + (float)acc1[5] * pd4.y
             + (float)acc1[6] * pd4.z + (float)acc1[7] * pd4.w;
    rr *= fac;
    // sum over ln (pairs) and qd (dim chunks): all 6 lane bits
    #pragma unroll
    for (int off = 1; off <= 32; off <<= 1) rr += __shfl_xor(rr, off, 64);

    if (lane == 0) out[r] = lin + rr / lsum;
}

extern "C" void kernel_launch(void* const* d_in, const int* in_sizes, int n_in,
                              void* d_out, int out_size, void* d_ws, size_t ws_size,
                              hipStream_t stream) {
    const int*   sparse = (const int*)  d_in[0];
    const float* dense  = (const float*)d_in[1];
    const float* etab   = (const float*)d_in[2];
    const float* ltab   = (const float*)d_in[3];
    const float* wdense = (const float*)d_in[4];
    const float* bias   = (const float*)d_in[5];
    const float* W1     = (const float*)d_in[6];
    const float* b1     = (const float*)d_in[7];
    const float* w2     = (const float*)d_in[8];
    const float* proj   = (const float*)d_in[9];
    float* outp = (float*)d_out;

    const int B = in_sizes[0] / NF;

    afm_kernel<<<dim3((B + WPB - 1) / WPB), dim3(BLOCK), 0, stream>>>(
        sparse, dense, etab, ltab, wdense, bias, W1, b1, w2, proj, outp, B);
    (void)n_in; (void)out_size; (void)d_ws; (void)ws_size;
}